// Round 1
// baseline (180.075 us; speedup 1.0000x reference)
//
#include <hip/hip_runtime.h>
#include <math.h>

#define TSZ 64
#define USZ 8
#define NB  32          // batches per block in main kernel
#define XS  68          // padded LDS row stride (floats); 68*4=272 bytes, %16==0

// ws layout (floats): [0..511] w[u][s] (u-major, stride 64); [512..519] a[u]; [520..527] bb[u]

__global__ void setup_kernel(const float* __restrict__ alpha,
                             const float* __restrict__ beta,
                             const float* __restrict__ gamma_,
                             const float* __restrict__ tauZ,
                             const float* __restrict__ nZ,
                             const float* __restrict__ tauC,
                             const float* __restrict__ nC,
                             float* __restrict__ ws) {
    __shared__ float kz[USZ][TSZ];
    __shared__ int ti_s[USZ];
    const int t = threadIdx.x;  // 0..63
    const float tf = (float)t;
    for (int u = 0; u < USZ; ++u) {
        float g     = gamma_[u] * 10.0f;
        float tau_c = tauC[u] * 100.0f;
        float n_c   = nC[u]   * 10.0f;
        float tau_z = tauZ[u] * 100.0f;
        float n_z   = nZ[u]   * 10.0f;
        // gamma_filter: t^n * exp(-t/tau) / tau^(n+1) / Gamma(n+1)
        float kc  = powf(tf, n_c) * expf(-tf / tau_c) / powf(tau_c, n_c + 1.0f) / tgammaf(n_c + 1.0f);
        float kzg = powf(tf, n_z) * expf(-tf / tau_z) / powf(tau_z, n_z + 1.0f) / tgammaf(n_z + 1.0f);
        kz[u][t] = g * kc + (1.0f - g) * kzg;
    }
    __syncthreads();
    if (t < USZ) {
        const int u = t;
        float best = kz[u][0];
        int bi = 0;
        for (int s = 1; s < TSZ; ++s) {
            float v = kz[u][s];
            if (v > best) { best = v; bi = s; }   // strict > => first-occurrence argmax, matches np
        }
        int ti = TSZ - bi;                         // T - z_shift
        if (ti > TSZ - 1) ti = TSZ - 1;
        if (ti < 0) ti = 0;
        ti_s[u] = ti;
        ws[512 + u] = alpha[u] * 100.0f;           // a
        ws[520 + u] = beta[u]  * 10.0f;            // bb
    }
    __syncthreads();
    for (int u = 0; u < USZ; ++u) {
        int ti = ti_s[u];
        ws[u * TSZ + t] = (t <= ti) ? kz[u][ti - t] : 0.0f;
    }
}

__global__ __launch_bounds__(256) void main_kernel(const float* __restrict__ x,
                                                   const float* __restrict__ ws,
                                                   float* __restrict__ out) {
    __shared__ __attribute__((aligned(16))) float xs[NB * XS];   // x tile, padded rows
    __shared__ __attribute__((aligned(16))) float wl[USZ * XS];  // weights, padded rows
    __shared__ __attribute__((aligned(16))) float fs[NB * USZ];  // per-(b,u) scale

    const int tid = threadIdx.x;
    const int blk = blockIdx.x;

    // Stage w (512 floats = 128 float4) into padded LDS
    if (tid < 128) {
        float4 v = ((const float4*)ws)[tid];
        int u  = tid >> 4;            // 16 float4 per row of 64
        int s0 = (tid & 15) << 2;
        *((float4*)&wl[u * XS + s0]) = v;
    }
    // Stage x tile (32 rows x 64 = 512 float4), coalesced
    const float4* x4 = (const float4*)(x + (size_t)blk * NB * TSZ);
    #pragma unroll
    for (int k = 0; k < 2; ++k) {
        int j = tid + k * 256;        // 0..511
        float4 v = x4[j];
        int bl = j >> 4;
        int s0 = (j & 15) << 2;
        *((float4*)&xs[bl * XS + s0]) = v;
    }
    __syncthreads();

    // One thread per (b_local, u): 64-tap dot product from LDS
    {
        const int bl = tid >> 3;
        const int u  = tid & 7;
        const float4* xr = (const float4*)&xs[bl * XS];
        const float4* wr = (const float4*)&wl[u * XS];
        float acc = 0.0f;
        #pragma unroll
        for (int j = 0; j < 16; ++j) {
            float4 a = xr[j];
            float4 b = wr[j];
            acc += a.x * b.x + a.y * b.y + a.z * b.z + a.w * b.w;
        }
        float av = ws[512 + u];
        float bv = ws[520 + u];
        fs[bl * USZ + u] = av / (1.0f + bv * acc);
    }
    __syncthreads();

    // Stream the 32*512 = 16384-float output tile, fully coalesced float4
    float4* o4 = (float4*)(out + (size_t)blk * NB * TSZ * USZ);
    #pragma unroll
    for (int k = 0; k < 16; ++k) {
        int j = tid + k * 256;        // float4 idx within block tile, 0..4095
        int bl   = j >> 7;            // 128 float4 per batch row
        int r    = j & 127;
        int t    = r >> 1;
        int half = r & 1;
        float xv = xs[bl * XS + t];
        float4 f = *((const float4*)&fs[bl * USZ + half * 4]);
        float4 o;
        o.x = xv * f.x; o.y = xv * f.y; o.z = xv * f.z; o.w = xv * f.w;
        o4[j] = o;
    }
}

extern "C" void kernel_launch(void* const* d_in, const int* in_sizes, int n_in,
                              void* d_out, int out_size, void* d_ws, size_t ws_size,
                              hipStream_t stream) {
    const float* inputs = (const float*)d_in[0];
    const float* alpha  = (const float*)d_in[1];
    const float* beta   = (const float*)d_in[2];
    const float* gamma_ = (const float*)d_in[3];
    // d_in[4] zeta, d_in[5] tauY, d_in[6] nY: unused by reference
    const float* tauZ   = (const float*)d_in[7];
    const float* nZ     = (const float*)d_in[8];
    const float* tauC   = (const float*)d_in[9];
    const float* nC     = (const float*)d_in[10];
    float* out = (float*)d_out;
    float* ws  = (float*)d_ws;

    setup_kernel<<<1, 64, 0, stream>>>(alpha, beta, gamma_, tauZ, nZ, tauC, nC, ws);

    const int B = in_sizes[0] / TSZ;      // 65536
    main_kernel<<<B / NB, 256, 0, stream>>>(inputs, ws, out);
}

// Round 3
// 173.349 us; speedup vs baseline: 1.0388x; 1.0388x over previous
//
#include <hip/hip_runtime.h>
#include <math.h>

#define TSZ 64
#define USZ 8
#define NB  16          // batches per block in main kernel
#define XS  68          // padded LDS row stride (floats); 68*4=272 bytes, %16==0

typedef float nfloat4 __attribute__((ext_vector_type(4)));   // native vec for NT store

// ws layout (floats): [0..511] w[u][s] (u-major, stride 64); [512..519] a[u]; [520..527] bb[u]

__global__ __launch_bounds__(1024) void setup_kernel(const float* __restrict__ alpha,
                             const float* __restrict__ beta,
                             const float* __restrict__ gamma_,
                             const float* __restrict__ tauZ,
                             const float* __restrict__ nZ,
                             const float* __restrict__ tauC,
                             const float* __restrict__ nC,
                             float* __restrict__ ws) {
    __shared__ float kbuf[2][USZ][TSZ];   // [0]=Kc, [1]=Kz_gamma
    __shared__ float kz[USZ][TSZ];
    __shared__ int ti_s[USZ];

    const int tid = threadIdx.x;          // 0..1023
    {
        // one gamma_filter evaluation per thread
        const int fid = tid >> 9;         // 0: Kc, 1: Kz-part
        const int rem = tid & 511;
        const int u   = rem >> 6;
        const int t   = rem & 63;
        const float tf = (float)t;
        float tau, n;
        if (fid == 0) { tau = tauC[u] * 100.0f; n = nC[u] * 10.0f; }
        else          { tau = tauZ[u] * 100.0f; n = nZ[u] * 10.0f; }
        float f = powf(tf, n) * expf(-tf / tau) / powf(tau, n + 1.0f) / tgammaf(n + 1.0f);
        kbuf[fid][u][t] = f;
    }
    __syncthreads();
    if (tid < 512) {
        const int u = tid >> 6;
        const int t = tid & 63;
        float g = gamma_[u] * 10.0f;
        kz[u][t] = g * kbuf[0][u][t] + (1.0f - g) * kbuf[1][u][t];
    }
    __syncthreads();
    if (tid < USZ) {
        const int u = tid;
        float best = kz[u][0];
        int bi = 0;
        for (int s = 1; s < TSZ; ++s) {
            float v = kz[u][s];
            if (v > best) { best = v; bi = s; }   // strict > => first-occurrence argmax (np semantics)
        }
        int ti = TSZ - bi;                         // T - z_shift
        if (ti > TSZ - 1) ti = TSZ - 1;
        if (ti < 0) ti = 0;
        ti_s[u] = ti;
        ws[512 + u] = alpha[u] * 100.0f;           // a
        ws[520 + u] = beta[u]  * 10.0f;            // bb
    }
    __syncthreads();
    if (tid < 512) {
        const int u = tid >> 6;
        const int t = tid & 63;
        int ti = ti_s[u];
        ws[u * TSZ + t] = (t <= ti) ? kz[u][ti - t] : 0.0f;
    }
}

__global__ __launch_bounds__(256) void main_kernel(const float* __restrict__ x,
                                                   const float* __restrict__ ws,
                                                   float* __restrict__ out) {
    __shared__ __attribute__((aligned(16))) float xs[NB * XS];   // x tile, padded rows
    __shared__ __attribute__((aligned(16))) float wl[USZ * XS];  // weights, padded rows
    __shared__ __attribute__((aligned(16))) float fs[NB * USZ];  // per-(b,u) scale

    const int tid = threadIdx.x;
    const int blk = blockIdx.x;

    // Stage w (512 floats = 128 float4) into padded LDS
    if (tid < 128) {
        float4 v = ((const float4*)ws)[tid];
        int u  = tid >> 4;            // 16 float4 per row of 64
        int s0 = (tid & 15) << 2;
        *((float4*)&wl[u * XS + s0]) = v;
    }
    // Stage x tile (16 rows x 64 floats = 256 float4), coalesced, one per thread
    {
        const float4* x4 = (const float4*)(x + (size_t)blk * NB * TSZ);
        float4 v = x4[tid];
        int bl = tid >> 4;
        int s0 = (tid & 15) << 2;
        *((float4*)&xs[bl * XS + s0]) = v;
    }
    __syncthreads();

    // One thread per (b_local, u): 64-tap dot product from LDS (128 threads active)
    if (tid < NB * USZ) {
        const int bl = tid >> 3;
        const int u  = tid & 7;
        const float4* xr = (const float4*)&xs[bl * XS];
        const float4* wr = (const float4*)&wl[u * XS];
        float acc = 0.0f;
        #pragma unroll
        for (int j = 0; j < 16; ++j) {
            float4 a = xr[j];
            float4 b = wr[j];
            acc += a.x * b.x + a.y * b.y + a.z * b.z + a.w * b.w;
        }
        float av = ws[512 + u];
        float bv = ws[520 + u];
        fs[bl * USZ + u] = av / (1.0f + bv * acc);
    }
    __syncthreads();

    // Stream the 16*512 = 8192-float output tile, fully coalesced float4, non-temporal
    nfloat4* o4 = (nfloat4*)(out + (size_t)blk * NB * TSZ * USZ);
    #pragma unroll
    for (int k = 0; k < 8; ++k) {
        int j = tid + k * 256;        // float4 idx within block tile, 0..2047
        int bl   = j >> 7;            // 128 float4 per batch row
        int r    = j & 127;
        int t    = r >> 1;
        int half = r & 1;
        float xv = xs[bl * XS + t];
        float4 f = *((const float4*)&fs[bl * USZ + half * 4]);
        nfloat4 o;
        o.x = xv * f.x; o.y = xv * f.y; o.z = xv * f.z; o.w = xv * f.w;
        __builtin_nontemporal_store(o, &o4[j]);
    }
}

extern "C" void kernel_launch(void* const* d_in, const int* in_sizes, int n_in,
                              void* d_out, int out_size, void* d_ws, size_t ws_size,
                              hipStream_t stream) {
    const float* inputs = (const float*)d_in[0];
    const float* alpha  = (const float*)d_in[1];
    const float* beta   = (const float*)d_in[2];
    const float* gamma_ = (const float*)d_in[3];
    // d_in[4] zeta, d_in[5] tauY, d_in[6] nY: unused by reference
    const float* tauZ   = (const float*)d_in[7];
    const float* nZ     = (const float*)d_in[8];
    const float* tauC   = (const float*)d_in[9];
    const float* nC     = (const float*)d_in[10];
    float* out = (float*)d_out;
    float* ws  = (float*)d_ws;

    setup_kernel<<<1, 1024, 0, stream>>>(alpha, beta, gamma_, tauZ, nZ, tauC, nC, ws);

    const int B = in_sizes[0] / TSZ;      // 65536
    main_kernel<<<B / NB, 256, 0, stream>>>(inputs, ws, out);
}